// Round 1
// baseline (2095.397 us; speedup 1.0000x reference)
//
#include <hip/hip_runtime.h>
#include <math.h>

#define BS   64
#define DIM  512
#define SRC  400
#define TDEC 100
#define NEMB 50257
#define K3   1536   // 3*DIM

// workspace float offsets
#define WS_Q    0          // [2][64][512]
#define WS_AENC 65536      // [64][400]
#define WS_ADEC 91136      // [64][100]
#define WS_CENC 97536      // [64][512]
#define WS_CDEC 130304     // [64][512]
#define WS_CCT  163072     // [1536][64]  (c_cat, [j][b])
#define WS_PSW  261376     // [64]
#define WS_SMAX 261440     // [64]
#define WS_SSUM 261504     // [64]

// ---------------- q = h_t @ W_attn  (per b, per enc/dec) ----------------
__global__ void k_qk(const float* __restrict__ h_t,
                     const float* __restrict__ Wenc,
                     const float* __restrict__ Wdec,
                     float* __restrict__ ws) {
    const int b = blockIdx.x, which = blockIdx.y, tid = threadIdx.x;
    const float* W = which ? Wdec : Wenc;
    float* q = ws + WS_Q + which * (BS * DIM) + b * DIM;
    __shared__ float ht[DIM];
    ht[tid]       = h_t[b * DIM + tid];
    ht[tid + 256] = h_t[b * DIM + tid + 256];
    __syncthreads();
    float a0 = 0.f, a1 = 0.f;
    #pragma unroll 4
    for (int k = 0; k < DIM; ++k) {
        float hv = ht[k];
        a0 += hv * W[k * DIM + tid];
        a1 += hv * W[k * DIM + tid + 256];
    }
    q[tid] = a0;
    q[tid + 256] = a1;
}

// ------------- E[b,i] = sum_d q[b,d]*hv[b,d,i]; A = E/sum(E) -------------
__global__ void k_attnE(const float* __restrict__ h_enc,
                        const float* __restrict__ h_dec,
                        float* __restrict__ ws) {
    const int b = blockIdx.x, which = blockIdx.y, tid = threadIdx.x;
    const int n = which ? TDEC : SRC;
    const float* h = which ? h_dec : h_enc;
    const float* q = ws + WS_Q + which * (BS * DIM) + b * DIM;
    float* A = ws + (which ? WS_ADEC : WS_AENC) + b * n;
    __shared__ float qs[DIM];
    __shared__ float red[512];
    qs[tid] = q[tid];   // exactly 512 threads
    __syncthreads();
    float e = 0.f;
    const float* hb = h + (size_t)b * DIM * n;
    if (tid < n) {
        #pragma unroll 4
        for (int d = 0; d < DIM; ++d) e += qs[d] * hb[(size_t)d * n + tid];
    }
    red[tid] = e;
    __syncthreads();
    for (int s = 256; s > 0; s >>= 1) {
        if (tid < s) red[tid] += red[tid + s];
        __syncthreads();
    }
    const float tot = red[0];
    if (tid < n) A[tid] = e / tot;
}

// ----------------- C[b,d] = sum_i hv[b,d,i]*A[b,i] -----------------------
__global__ void k_attnC(const float* __restrict__ h_enc,
                        const float* __restrict__ h_dec,
                        float* __restrict__ ws) {
    const int b = blockIdx.x, which = blockIdx.y, tid = threadIdx.x;
    const int n = which ? TDEC : SRC;
    const float* h = which ? h_dec : h_enc;
    const float* A = ws + (which ? WS_ADEC : WS_AENC) + b * n;
    float* C = ws + (which ? WS_CDEC : WS_CENC) + b * DIM;
    __shared__ float As[SRC];
    if (tid < n) As[tid] = A[tid];
    if (tid + 256 < n) As[tid + 256] = A[tid + 256];
    __syncthreads();
    const float* hb = h + (size_t)b * DIM * n;
    for (int r = 0; r < 2; ++r) {
        const int d = tid + r * 256;
        const float* row = hb + (size_t)d * n;
        float acc = 0.f;
        #pragma unroll 4
        for (int i = 0; i < n; i += 4) {
            float4 v = *(const float4*)(row + i);
            acc += v.x * As[i] + v.y * As[i + 1] + v.z * As[i + 2] + v.w * As[i + 3];
        }
        C[d] = acc;
    }
}

// --- c_cat assembly (ccT[j][b]), p_switch = sigmoid(W_u@c_cat+b_u), p_copy ---
__global__ void k_pswitch(const float* __restrict__ h_t,
                          const float* __restrict__ W_u,
                          const float* __restrict__ b_u,
                          float* __restrict__ out_copy,
                          float* __restrict__ ws) {
    const int b = blockIdx.x, tid = threadIdx.x;
    const float* Ce = ws + WS_CENC + b * DIM;
    const float* Cd = ws + WS_CDEC + b * DIM;
    float* ccT = ws + WS_CCT;
    __shared__ float red[256];
    float part = 0.f;
    #pragma unroll
    for (int r = 0; r < 6; ++r) {
        const int j = tid + r * 256;
        float v = (j < DIM) ? h_t[b * DIM + j]
                            : ((j < 2 * DIM) ? Ce[j - DIM] : Cd[j - 2 * DIM]);
        ccT[(size_t)j * BS + b] = v;
        part += W_u[j] * v;
    }
    red[tid] = part;
    __syncthreads();
    for (int s = 128; s > 0; s >>= 1) {
        if (tid < s) red[tid] += red[tid + s];
        __syncthreads();
    }
    const float ps = 1.f / (1.f + expf(-(red[0] + b_u[0])));
    if (tid == 0) ws[WS_PSW + b] = ps;
    const float* Ae = ws + WS_AENC + b * SRC;
    for (int i = tid; i < SRC; i += 256) out_copy[b * SRC + i] = ps * Ae[i];
}

// --- fused: logits[v,b] = tanh(We[v,:]@Wp)[:]@ccT[:,b] + b_out[v] → d_out ---
#define MT 32
#define JT 256
#define KC 128
__global__ __launch_bounds__(512) void k_big(const float* __restrict__ We,
                                             const float* __restrict__ Wp,
                                             const float* __restrict__ b_out,
                                             const float* __restrict__ ws,
                                             float* __restrict__ out) {
    __shared__ float WeT[KC][MT + 4];   // [k][m], pad for banks/alignment
    __shared__ float Tt[JT][MT + 4];    // [j][m], tanh'd tile
    __shared__ float Lbuf[MT][BS + 1];  // logits transpose buffer
    const int tid = threadIdx.x;
    const int v0 = blockIdx.x * MT;
    const int mg = tid >> 6;      // 0..7
    const int jg = tid & 63;      // 0..63  (also the b-lane in GEMM2)
    const int m0 = mg * 4;
    const int j0 = jg * 4;
    const float* ccT = ws + WS_CCT;
    float acc2[4] = {0.f, 0.f, 0.f, 0.f};

    for (int jc = 0; jc < K3 / JT; ++jc) {
        float acc[4][4];
        #pragma unroll
        for (int a = 0; a < 4; ++a)
            #pragma unroll
            for (int c = 0; c < 4; ++c) acc[a][c] = 0.f;

        for (int kc = 0; kc < DIM / KC; ++kc) {
            __syncthreads();
            // stage We chunk: [32 m][128 k] -> WeT[k][m]
            #pragma unroll
            for (int r = 0; r < (MT * KC) / 512; ++r) {
                const int idx = r * 512 + tid;
                const int m = idx >> 7;
                const int k = idx & (KC - 1);
                WeT[k][m] = (v0 + m < NEMB) ? We[(size_t)(v0 + m) * DIM + kc * KC + k] : 0.f;
            }
            __syncthreads();
            const float* wpb = Wp + (size_t)(kc * KC) * K3 + jc * JT + j0;
            #pragma unroll 4
            for (int k = 0; k < KC; ++k) {
                const float4 wp = *(const float4*)(wpb + (size_t)k * K3);
                const float4 we = *(const float4*)&WeT[k][m0];
                acc[0][0] += we.x * wp.x; acc[0][1] += we.x * wp.y; acc[0][2] += we.x * wp.z; acc[0][3] += we.x * wp.w;
                acc[1][0] += we.y * wp.x; acc[1][1] += we.y * wp.y; acc[1][2] += we.y * wp.z; acc[1][3] += we.y * wp.w;
                acc[2][0] += we.z * wp.x; acc[2][1] += we.z * wp.y; acc[2][2] += we.z * wp.z; acc[2][3] += we.z * wp.w;
                acc[3][0] += we.w * wp.x; acc[3][1] += we.w * wp.y; acc[3][2] += we.w * wp.z; acc[3][3] += we.w * wp.w;
            }
        }
        __syncthreads();   // prior GEMM2 readers of Tt are done
        #pragma unroll
        for (int jj = 0; jj < 4; ++jj) {
            float4 tv;
            tv.x = tanhf(acc[0][jj]);
            tv.y = tanhf(acc[1][jj]);
            tv.z = tanhf(acc[2][jj]);
            tv.w = tanhf(acc[3][jj]);
            *(float4*)&Tt[j0 + jj][m0] = tv;
        }
        __syncthreads();
        // GEMM2: logits[m0..m0+3][jg] += Tt[:, m]^T . ccT[:, jg]
        const float* cb = ccT + (size_t)jc * JT * BS + jg;
        #pragma unroll 4
        for (int j = 0; j < JT; ++j) {
            const float c = cb[(size_t)j * BS];
            const float4 t = *(const float4*)&Tt[j][m0];
            acc2[0] += t.x * c; acc2[1] += t.y * c; acc2[2] += t.z * c; acc2[3] += t.w * c;
        }
    }
    __syncthreads();
    #pragma unroll
    for (int mm = 0; mm < 4; ++mm) Lbuf[m0 + mm][jg] = acc2[mm];
    __syncthreads();
    // coalesced store of logits into the p_gen region: out[b*NEMB + v]
    #pragma unroll
    for (int r = 0; r < 4; ++r) {
        const int idx = r * 512 + tid;
        const int m = idx & (MT - 1);
        const int b = idx >> 5;
        const int v = v0 + m;
        if (v < NEMB) out[(size_t)b * NEMB + v] = Lbuf[m][b] + b_out[v];
    }
}

// -------- per-column (per b) softmax stats over the vocab dimension --------
__global__ void k_colreduce(const float* __restrict__ out, float* __restrict__ ws) {
    const int b = blockIdx.x, tid = threadIdx.x;
    const float* L = out + (size_t)b * NEMB;
    __shared__ float red[256];
    float m = -1e30f;
    for (int v = tid; v < NEMB; v += 256) m = fmaxf(m, L[v]);
    red[tid] = m;
    __syncthreads();
    for (int s = 128; s > 0; s >>= 1) {
        if (tid < s) red[tid] = fmaxf(red[tid], red[tid + s]);
        __syncthreads();
    }
    const float mb = red[0];
    __syncthreads();
    float sum = 0.f;
    for (int v = tid; v < NEMB; v += 256) sum += expf(L[v] - mb);
    red[tid] = sum;
    __syncthreads();
    for (int s = 128; s > 0; s >>= 1) {
        if (tid < s) red[tid] += red[tid + s];
        __syncthreads();
    }
    if (tid == 0) { ws[WS_SMAX + b] = mb; ws[WS_SSUM + b] = red[0]; }
}

// -------- p_gen[b,v] = (1-p_switch[b]) * softmax(logits)[v,b], in place ----
__global__ void k_finalize(float* __restrict__ out, const float* __restrict__ ws) {
    const int total = BS * NEMB;
    const int stride = gridDim.x * blockDim.x;
    for (int idx = blockIdx.x * blockDim.x + threadIdx.x; idx < total; idx += stride) {
        const int b = idx / NEMB;
        const float mb = ws[WS_SMAX + b];
        const float sb = ws[WS_SSUM + b];
        const float ps = ws[WS_PSW + b];
        out[idx] = (1.f - ps) * expf(out[idx] - mb) / sb;
    }
}

extern "C" void kernel_launch(void* const* d_in, const int* in_sizes, int n_in,
                              void* d_out, int out_size, void* d_ws, size_t ws_size,
                              hipStream_t stream) {
    const float* h_t        = (const float*)d_in[0];
    const float* h_enc      = (const float*)d_in[1];
    const float* h_dec      = (const float*)d_in[2];
    // d_in[3] = x (int), unused by the reference computation
    const float* W_attn_enc = (const float*)d_in[4];
    const float* W_attn_dec = (const float*)d_in[5];
    const float* W_emb      = (const float*)d_in[6];
    const float* W_proj     = (const float*)d_in[7];
    const float* W_u        = (const float*)d_in[8];
    const float* b_u        = (const float*)d_in[9];
    const float* b_out      = (const float*)d_in[10];

    float* out = (float*)d_out;
    float* ws  = (float*)d_ws;
    float* out_copy = out + (size_t)BS * NEMB;

    k_qk     <<<dim3(64, 2), 256, 0, stream>>>(h_t, W_attn_enc, W_attn_dec, ws);
    k_attnE  <<<dim3(64, 2), 512, 0, stream>>>(h_enc, h_dec, ws);
    k_attnC  <<<dim3(64, 2), 256, 0, stream>>>(h_enc, h_dec, ws);
    k_pswitch<<<64, 256, 0, stream>>>(h_t, W_u, b_u, out_copy, ws);
    k_big    <<<(NEMB + MT - 1) / MT, 512, 0, stream>>>(W_emb, W_proj, b_out, ws, out);
    k_colreduce<<<64, 256, 0, stream>>>(out, ws);
    k_finalize <<<4096, 256, 0, stream>>>(out, ws);
}

// Round 2
// 555.278 us; speedup vs baseline: 3.7736x; 3.7736x over previous
//
#include <hip/hip_runtime.h>
#include <math.h>

typedef __attribute__((ext_vector_type(8))) short bf16x8;
typedef __attribute__((ext_vector_type(4))) float f32x4;

#define BS   64
#define DIM  512
#define SRC  400
#define TDEC 100
#define NEMB 50257
#define K3   1536   // 3*DIM

// workspace float offsets
#define WS_Q    0          // [2][64][512]
#define WS_AENC 65536      // [64][400]
#define WS_ADEC 91136      // [64][100]
#define WS_CENC 97536      // [64][512]
#define WS_CDEC 130304     // [64][512]
#define WS_PSW  163072     // [64]
#define WS_SMAX 163136     // [64]
#define WS_SSUM 163200     // [64]
#define WS_WPT  163264     // ushort[1536*512]  = 393216 f32 slots
#define WS_CCB  556480     // ushort[64*1536]   = 49152 f32 slots

__device__ __forceinline__ ushort f2bf(float x) {
    union { float f; unsigned u; } v; v.f = x;
    unsigned r = (v.u + 0x7FFFu + ((v.u >> 16) & 1u)) >> 16;
    return (ushort)r;
}
__device__ __forceinline__ float fast_tanh(float x) {
    float e = __expf(2.0f * x);
    return 1.0f - 2.0f / (e + 1.0f);
}

// ---------------- q = h_t @ W_attn  (per b, per enc/dec) ----------------
__global__ void k_qk(const float* __restrict__ h_t,
                     const float* __restrict__ Wenc,
                     const float* __restrict__ Wdec,
                     float* __restrict__ ws) {
    const int b = blockIdx.x, which = blockIdx.y, tid = threadIdx.x;
    const float* W = which ? Wdec : Wenc;
    float* q = ws + WS_Q + which * (BS * DIM) + b * DIM;
    __shared__ float ht[DIM];
    ht[tid]       = h_t[b * DIM + tid];
    ht[tid + 256] = h_t[b * DIM + tid + 256];
    __syncthreads();
    float a0 = 0.f, a1 = 0.f;
    #pragma unroll 4
    for (int k = 0; k < DIM; ++k) {
        float hv = ht[k];
        a0 += hv * W[k * DIM + tid];
        a1 += hv * W[k * DIM + tid + 256];
    }
    q[tid] = a0;
    q[tid + 256] = a1;
}

// ------------- E[b,i] = sum_d q[b,d]*hv[b,d,i]; A = E/sum(E) -------------
__global__ void k_attnE(const float* __restrict__ h_enc,
                        const float* __restrict__ h_dec,
                        float* __restrict__ ws) {
    const int b = blockIdx.x, which = blockIdx.y, tid = threadIdx.x;
    const int n = which ? TDEC : SRC;
    const float* h = which ? h_dec : h_enc;
    const float* q = ws + WS_Q + which * (BS * DIM) + b * DIM;
    float* A = ws + (which ? WS_ADEC : WS_AENC) + b * n;
    __shared__ float qs[DIM];
    __shared__ float red[512];
    qs[tid] = q[tid];   // exactly 512 threads
    __syncthreads();
    float e = 0.f;
    const float* hb = h + (size_t)b * DIM * n;
    if (tid < n) {
        #pragma unroll 4
        for (int d = 0; d < DIM; ++d) e += qs[d] * hb[(size_t)d * n + tid];
    }
    red[tid] = e;
    __syncthreads();
    for (int s = 256; s > 0; s >>= 1) {
        if (tid < s) red[tid] += red[tid + s];
        __syncthreads();
    }
    const float tot = red[0];
    if (tid < n) A[tid] = e / tot;
}

// ----------------- C[b,d] = sum_i hv[b,d,i]*A[b,i] -----------------------
__global__ void k_attnC(const float* __restrict__ h_enc,
                        const float* __restrict__ h_dec,
                        float* __restrict__ ws) {
    const int b = blockIdx.x, which = blockIdx.y, tid = threadIdx.x;
    const int n = which ? TDEC : SRC;
    const float* h = which ? h_dec : h_enc;
    const float* A = ws + (which ? WS_ADEC : WS_AENC) + b * n;
    float* C = ws + (which ? WS_CDEC : WS_CENC) + b * DIM;
    __shared__ float As[SRC];
    if (tid < n) As[tid] = A[tid];
    if (tid + 256 < n) As[tid + 256] = A[tid + 256];
    __syncthreads();
    const float* hb = h + (size_t)b * DIM * n;
    for (int r = 0; r < 2; ++r) {
        const int d = tid + r * 256;
        const float* row = hb + (size_t)d * n;
        float acc = 0.f;
        #pragma unroll 4
        for (int i = 0; i < n; i += 4) {
            float4 v = *(const float4*)(row + i);
            acc += v.x * As[i] + v.y * As[i + 1] + v.z * As[i + 2] + v.w * As[i + 3];
        }
        C[d] = acc;
    }
}

// --------- Wp [512][1536] f32 -> WpT [1536 j][512 k] bf16 -----------------
__global__ void k_prepWpT(const float* __restrict__ Wp, float* __restrict__ ws) {
    ushort* WpT = (ushort*)(ws + WS_WPT);
    const int idx = (blockIdx.x * 256 + threadIdx.x) * 4;   // 768 blocks exact
    const int j = idx >> 9, k0 = idx & 511;
    ushort4 o;
    o.x = f2bf(Wp[(size_t)(k0 + 0) * K3 + j]);
    o.y = f2bf(Wp[(size_t)(k0 + 1) * K3 + j]);
    o.z = f2bf(Wp[(size_t)(k0 + 2) * K3 + j]);
    o.w = f2bf(Wp[(size_t)(k0 + 3) * K3 + j]);
    *(ushort4*)(WpT + idx) = o;
}

// --- ccB[b][1536] bf16, p_switch = sigmoid(W_u@c_cat+b_u), p_copy ---------
__global__ void k_pswitch(const float* __restrict__ h_t,
                          const float* __restrict__ W_u,
                          const float* __restrict__ b_u,
                          float* __restrict__ out_copy,
                          float* __restrict__ ws) {
    const int b = blockIdx.x, tid = threadIdx.x;
    const float* Ce = ws + WS_CENC + b * DIM;
    const float* Cd = ws + WS_CDEC + b * DIM;
    ushort* ccB = (ushort*)(ws + WS_CCB);
    __shared__ float red[256];
    float part = 0.f;
    #pragma unroll
    for (int r = 0; r < 6; ++r) {
        const int j = tid + r * 256;
        float v = (j < DIM) ? h_t[b * DIM + j]
                            : ((j < 2 * DIM) ? Ce[j - DIM] : Cd[j - 2 * DIM]);
        ccB[(size_t)b * K3 + j] = f2bf(v);
        part += W_u[j] * v;
    }
    red[tid] = part;
    __syncthreads();
    for (int s = 128; s > 0; s >>= 1) {
        if (tid < s) red[tid] += red[tid + s];
        __syncthreads();
    }
    const float ps = 1.f / (1.f + expf(-(red[0] + b_u[0])));
    if (tid == 0) ws[WS_PSW + b] = ps;
    const float* Ae = ws + WS_AENC + b * SRC;
    for (int i = tid; i < SRC; i += 256) out_copy[b * SRC + i] = ps * Ae[i];
}

// ---- MFMA fused: logits[v][b] = tanh(We@Wp)[v,:] @ ccB[b,:] + b_out[v] ----
#define VB 32
__global__ __launch_bounds__(256) void k_bigmm(const float* __restrict__ We,
                                               const float* __restrict__ ws,
                                               const float* __restrict__ b_out,
                                               float* __restrict__ out) {
    __shared__ __align__(16) char smem[49152];
    ushort* WeS = (ushort*)smem;             // [32 v][512 k] bf16, XOR-swizzled (32 KB)
    char*   Tscb = smem + 32768;             // [4 w][32 v][64 j] bf16, swizzled (16 KB)
    float*  Lred = (float*)smem;             // [4 w][32 v][65 b] f32 (33280 B, overlaps)

    const ushort* WpT = (const ushort*)(ws + WS_WPT);
    const ushort* ccB = (const ushort*)(ws + WS_CCB);

    const int tid  = threadIdx.x;
    const int w    = tid >> 6, lane = tid & 63;
    const int lrow = lane & 15, lgrp = lane >> 4;
    const int v0   = blockIdx.x * VB;

    // ---- stage We rows -> bf16 LDS, swizzle byte ^= (v&15)<<4 ----
    for (int it = 0; it < 8; ++it) {
        const int idx = it * 256 + tid;
        const int v = idx >> 6;
        const int k0 = (idx & 63) * 8;
        const int row = v0 + v;
        float4 f0 = {0.f, 0.f, 0.f, 0.f}, f1 = {0.f, 0.f, 0.f, 0.f};
        if (row < NEMB) {
            f0 = *(const float4*)(We + (size_t)row * DIM + k0);
            f1 = *(const float4*)(We + (size_t)row * DIM + k0 + 4);
        }
        union { ushort us[8]; bf16x8 v8; } pk;
        pk.us[0] = f2bf(f0.x); pk.us[1] = f2bf(f0.y); pk.us[2] = f2bf(f0.z); pk.us[3] = f2bf(f0.w);
        pk.us[4] = f2bf(f1.x); pk.us[5] = f2bf(f1.y); pk.us[6] = f2bf(f1.z); pk.us[7] = f2bf(f1.w);
        *(bf16x8*)((char*)WeS + v * 1024 + ((k0 * 2) ^ ((v & 15) << 4))) = pk.v8;
    }
    __syncthreads();

    f32x4 La[8];
    #pragma unroll
    for (int i = 0; i < 8; ++i) La[i] = (f32x4){0.f, 0.f, 0.f, 0.f};

    char* tbase = Tscb + w * 4096;
    const int swz0 = (lrow & 15) << 4;          // WeS row lrow
    const int swz1 = ((16 + lrow) & 15) << 4;   // WeS row 16+lrow
    const int tswz0 = (lrow & 7) << 4;          // Tsc row lrow
    const int tswz1 = ((16 + lrow) & 7) << 4;   // Tsc row 16+lrow

    for (int t = 0; t < 6; ++t) {
        const int jc = w + 4 * t;
        const int j0 = jc * 64;
        f32x4 Ta[8];
        #pragma unroll
        for (int i = 0; i < 8; ++i) Ta[i] = (f32x4){0.f, 0.f, 0.f, 0.f};

        // ---- GEMM1: T[32][64] += WeS[32][512] @ WpT^T slice ----
        #pragma unroll 4
        for (int ks = 0; ks < 16; ++ks) {
            const int kb = ks * 64 + lgrp * 16;       // byte offset of k*2
            bf16x8 a0 = *(bf16x8*)((char*)WeS + lrow * 1024 + (kb ^ swz0));
            bf16x8 a1 = *(bf16x8*)((char*)WeS + (16 + lrow) * 1024 + (kb ^ swz1));
            const int kk = ks * 32 + lgrp * 8;
            #pragma unroll
            for (int nj = 0; nj < 4; ++nj) {
                const int j = j0 + nj * 16 + lrow;
                bf16x8 bv = *(const bf16x8*)(WpT + (size_t)j * DIM + kk);
                Ta[nj]     = __builtin_amdgcn_mfma_f32_16x16x32_bf16(a0, bv, Ta[nj], 0, 0, 0);
                Ta[4 + nj] = __builtin_amdgcn_mfma_f32_16x16x32_bf16(a1, bv, Ta[4 + nj], 0, 0, 0);
            }
        }

        // ---- tanh -> bf16 -> per-wave LDS scratch (C-layout -> A-layout) ----
        #pragma unroll
        for (int i = 0; i < 8; ++i) {
            const int mv = i >> 2, nj = i & 3;
            const int jb = (nj * 16 + lrow) * 2;
            #pragma unroll
            for (int r = 0; r < 4; ++r) {
                const int v = mv * 16 + lgrp * 4 + r;
                const float th = fast_tanh(Ta[i][r]);
                *(ushort*)(tbase + v * 128 + (jb ^ ((v & 7) << 4))) = f2bf(th);
            }
        }

        // ---- GEMM2: La[32 v][64 b] += T[32][64] @ ccB^T slice ----
        #pragma unroll
        for (int ks2 = 0; ks2 < 2; ++ks2) {
            const int jbyte = ks2 * 64 + lgrp * 16;
            bf16x8 t0 = *(bf16x8*)(tbase + lrow * 128 + (jbyte ^ tswz0));
            bf16x8 t1 = *(bf16x8*)(tbase + (16 + lrow) * 128 + (jbyte ^ tswz1));
            const int jj = j0 + ks2 * 32 + lgrp * 8;
            #pragma unroll
            for (int nb = 0; nb < 4; ++nb) {
                bf16x8 cb = *(const bf16x8*)(ccB + (size_t)(nb * 16 + lrow) * K3 + jj);
                La[nb]     = __builtin_amdgcn_mfma_f32_16x16x32_bf16(t0, cb, La[nb], 0, 0, 0);
                La[4 + nb] = __builtin_amdgcn_mfma_f32_16x16x32_bf16(t1, cb, La[4 + nb], 0, 0, 0);
            }
        }
    }

    // ---- cross-wave reduction of logits partials ----
    __syncthreads();   // everyone done with WeS before overwrite
    #pragma unroll
    for (int i = 0; i < 8; ++i) {
        const int mv = i >> 2, nb = i & 3;
        const int b = nb * 16 + lrow;
        #pragma unroll
        for (int r = 0; r < 4; ++r) {
            const int v = mv * 16 + lgrp * 4 + r;
            Lred[w * 2080 + v * 65 + b] = La[i][r];
        }
    }
    __syncthreads();
    for (int it = 0; it < 8; ++it) {
        const int idx = it * 256 + tid;
        const int b = idx >> 5;
        const int v = idx & 31;
        if (v0 + v < NEMB) {
            const float s = Lred[v * 65 + b] + Lred[2080 + v * 65 + b]
                          + Lred[4160 + v * 65 + b] + Lred[6240 + v * 65 + b];
            out[(size_t)b * NEMB + v0 + v] = s + b_out[v0 + v];
        }
    }
}

// -------- per-column (per b) softmax stats over the vocab dimension --------
__global__ void k_colreduce(const float* __restrict__ out, float* __restrict__ ws) {
    const int b = blockIdx.x, tid = threadIdx.x;
    const float* L = out + (size_t)b * NEMB;
    __shared__ float red[256];
    float m = -1e30f;
    for (int v = tid; v < NEMB; v += 256) m = fmaxf(m, L[v]);
    red[tid] = m;
    __syncthreads();
    for (int s = 128; s > 0; s >>= 1) {
        if (tid < s) red[tid] = fmaxf(red[tid], red[tid + s]);
        __syncthreads();
    }
    const float mb = red[0];
    __syncthreads();
    float sum = 0.f;
    for (int v = tid; v < NEMB; v += 256) sum += expf(L[v] - mb);
    red[tid] = sum;
    __syncthreads();
    for (int s = 128; s > 0; s >>= 1) {
        if (tid < s) red[tid] += red[tid + s];
        __syncthreads();
    }
    if (tid == 0) { ws[WS_SMAX + b] = mb; ws[WS_SSUM + b] = red[0]; }
}

// -------- p_gen[b,v] = (1-p_switch[b]) * softmax(logits)[v,b], in place ----
__global__ void k_finalize(float* __restrict__ out, const float* __restrict__ ws) {
    const int total = BS * NEMB;
    const int stride = gridDim.x * blockDim.x;
    for (int idx = blockIdx.x * blockDim.x + threadIdx.x; idx < total; idx += stride) {
        const int b = idx / NEMB;
        const float mb = ws[WS_SMAX + b];
        const float sb = ws[WS_SSUM + b];
        const float ps = ws[WS_PSW + b];
        out[idx] = (1.f - ps) * expf(out[idx] - mb) / sb;
    }
}

extern "C" void kernel_launch(void* const* d_in, const int* in_sizes, int n_in,
                              void* d_out, int out_size, void* d_ws, size_t ws_size,
                              hipStream_t stream) {
    const float* h_t        = (const float*)d_in[0];
    const float* h_enc      = (const float*)d_in[1];
    const float* h_dec      = (const float*)d_in[2];
    // d_in[3] = x (int), unused by the reference computation
    const float* W_attn_enc = (const float*)d_in[4];
    const float* W_attn_dec = (const float*)d_in[5];
    const float* W_emb      = (const float*)d_in[6];
    const float* W_proj     = (const float*)d_in[7];
    const float* W_u        = (const float*)d_in[8];
    const float* b_u        = (const float*)d_in[9];
    const float* b_out      = (const float*)d_in[10];

    float* out = (float*)d_out;
    float* ws  = (float*)d_ws;
    float* out_copy = out + (size_t)BS * NEMB;

    k_qk     <<<dim3(64, 2), 256, 0, stream>>>(h_t, W_attn_enc, W_attn_dec, ws);
    k_prepWpT<<<768, 256, 0, stream>>>(W_proj, ws);
    k_attnE  <<<dim3(64, 2), 512, 0, stream>>>(h_enc, h_dec, ws);
    k_attnC  <<<dim3(64, 2), 256, 0, stream>>>(h_enc, h_dec, ws);
    k_pswitch<<<64, 256, 0, stream>>>(h_t, W_u, b_u, out_copy, ws);
    k_bigmm  <<<(NEMB + VB - 1) / VB, 256, 0, stream>>>(W_emb, ws, b_out, out);
    k_colreduce<<<64, 256, 0, stream>>>(out, ws);
    k_finalize <<<4096, 256, 0, stream>>>(out, ws);
}

// Round 3
// 534.216 us; speedup vs baseline: 3.9224x; 1.0394x over previous
//
#include <hip/hip_runtime.h>
#include <math.h>

typedef __attribute__((ext_vector_type(8))) short bf16x8;
typedef __attribute__((ext_vector_type(4))) float f32x4;

#define BS   64
#define DIM  512
#define SRC  400
#define TDEC 100
#define NEMB 50257
#define K3   1536   // 3*DIM

// workspace float offsets
#define WS_Q     0          // [2][64][512]
#define WS_EENC  65536      // [64][400]  raw E
#define WS_EDEC  91136      // [64][100]  raw E
#define WS_CENC  97536      // [64][512]  unnormalized C (atomic)
#define WS_CDEC  130304     // [64][512]
#define WS_ESUM  163072     // [2][64]
#define WS_PSW   163200     // [64]
#define WS_SMAX  163264     // [64]  (uint-encoded running max)
#define WS_SSUM  163328     // [64]
#define WS_WPT   163392     // ushort[1536*512]
#define WS_CCB   556608     // ushort[64*1536]
#define WS_ZBEG  WS_CENC
#define WS_ZCNT  (163392 - WS_CENC)   // 65856 floats to zero

__device__ __forceinline__ ushort f2bf(float x) {
    union { float f; unsigned u; } v; v.f = x;
    unsigned r = (v.u + 0x7FFFu + ((v.u >> 16) & 1u)) >> 16;
    return (ushort)r;
}
__device__ __forceinline__ float fast_tanh(float x) {
    float e = __expf(2.0f * x);
    return 1.0f - 2.0f / (e + 1.0f);
}
__device__ __forceinline__ unsigned fenc(float f) {
    unsigned b = __float_as_uint(f);
    return (b & 0x80000000u) ? ~b : (b | 0x80000000u);
}
__device__ __forceinline__ float fdec(unsigned k) {
    unsigned b = (k & 0x80000000u) ? (k & 0x7FFFFFFFu) : ~k;
    return __uint_as_float(b);
}

// ------------------------- zero the accumulators --------------------------
__global__ void k_zero(float* __restrict__ ws) {
    const int i = blockIdx.x * 256 + threadIdx.x;
    if (i < WS_ZCNT) ws[WS_ZBEG + i] = 0.f;
}

// ---------------- q = h_t @ W_attn  (per b, per enc/dec) ----------------
__global__ void k_qk(const float* __restrict__ h_t,
                     const float* __restrict__ Wenc,
                     const float* __restrict__ Wdec,
                     float* __restrict__ ws) {
    const int b = blockIdx.x, which = blockIdx.y, tid = threadIdx.x;
    const float* W = which ? Wdec : Wenc;
    float* q = ws + WS_Q + which * (BS * DIM) + b * DIM;
    __shared__ float ht[DIM];
    ht[tid]       = h_t[b * DIM + tid];
    ht[tid + 256] = h_t[b * DIM + tid + 256];
    __syncthreads();
    float a0 = 0.f, a1 = 0.f;
    #pragma unroll 4
    for (int k = 0; k < DIM; ++k) {
        float hv = ht[k];
        a0 += hv * W[k * DIM + tid];
        a1 += hv * W[k * DIM + tid + 256];
    }
    q[tid] = a0;
    q[tid + 256] = a1;
}

// ------- fused one-pass attention: E (raw), Esum, C (unnormalized) -------
// grid (64 b, 2 which, 4 split), 256 threads
#define IC 16
__global__ __launch_bounds__(256) void k_attn(const float* __restrict__ h_enc,
                                              const float* __restrict__ h_dec,
                                              float* __restrict__ ws) {
    const int b = blockIdx.x, which = blockIdx.y, z = blockIdx.z;
    const int tid = threadIdx.x;
    const int n   = which ? TDEC : SRC;
    const int per = which ? (TDEC / 4) : (SRC / 4);
    const int i_begin = z * per, i_end = i_begin + per;
    const float* h  = which ? h_dec : h_enc;
    const float* q  = ws + WS_Q + which * (BS * DIM) + b * DIM;
    float* wsE      = ws + (which ? WS_EDEC : WS_EENC) + b * n;
    float* Cws      = ws + (which ? WS_CDEC : WS_CENC) + b * DIM;
    const float* hb = h + (size_t)b * DIM * n;

    __shared__ float hS[DIM * (IC + 1)];   // [512][17] padded
    __shared__ float qs[DIM];
    __shared__ float Ered[256];
    __shared__ float Es[IC];

    qs[tid] = q[tid];
    qs[tid + 256] = q[tid + 256];

    const int ii = tid & (IC - 1);
    const int dg = tid >> 4;               // 16 groups x 32 d
    float c0 = 0.f, c1 = 0.f, esum = 0.f;

    for (int i0 = i_begin; i0 < i_end; i0 += IC) {
        const int ic = min(IC, i_end - i0);
        __syncthreads();                    // protect hS/Es from prev iter readers
        #pragma unroll 8
        for (int idx = tid; idx < DIM * IC; idx += 256) {
            const int d = idx >> 4, i = idx & (IC - 1);
            hS[d * (IC + 1) + i] = (i < ic) ? hb[(size_t)d * n + i0 + i] : 0.f;
        }
        __syncthreads();
        // E partials: 16 i-lanes x 16 d-groups
        float p = 0.f;
        #pragma unroll 8
        for (int d = dg * 32; d < dg * 32 + 32; ++d) p += qs[d] * hS[d * (IC + 1) + ii];
        Ered[dg * IC + ii] = p;
        __syncthreads();
        if (tid < IC) {
            float e = 0.f;
            #pragma unroll
            for (int g = 0; g < 16; ++g) e += Ered[g * IC + tid];
            Es[tid] = e;
            esum += e;                      // pad lanes contribute 0
            if (tid < ic) wsE[i0 + tid] = e;
        }
        __syncthreads();
        // C accumulation: thread owns rows tid, tid+256
        #pragma unroll
        for (int i = 0; i < IC; ++i) {
            const float e = Es[i];
            c0 += hS[tid * (IC + 1) + i] * e;
            c1 += hS[(tid + 256) * (IC + 1) + i] * e;
        }
    }
    atomicAdd(&Cws[tid], c0);
    atomicAdd(&Cws[tid + 256], c1);
    __syncthreads();
    if (tid < IC) Ered[tid] = esum;
    __syncthreads();
    if (tid == 0) {
        float s = 0.f;
        #pragma unroll
        for (int g = 0; g < IC; ++g) s += Ered[g];
        atomicAdd(&ws[WS_ESUM + which * 64 + b], s);
    }
}

// --------- Wp [512][1536] f32 -> WpT [1536 j][512 k] bf16 (LDS tile) -------
__global__ void k_prepWpT(const float* __restrict__ Wp, float* __restrict__ ws) {
    __shared__ float tile[64][65];
    ushort* WpT = (ushort*)(ws + WS_WPT);
    const int j0 = blockIdx.x * 64, k0 = blockIdx.y * 64, tid = threadIdx.x;
    const int jj = (tid & 15) * 4, kk = tid >> 4;
    #pragma unroll
    for (int p = 0; p < 4; ++p) {
        const int k = kk + p * 16;
        const float4 v = *(const float4*)(Wp + (size_t)(k0 + k) * K3 + j0 + jj);
        tile[k][jj + 0] = v.x; tile[k][jj + 1] = v.y;
        tile[k][jj + 2] = v.z; tile[k][jj + 3] = v.w;
    }
    __syncthreads();
    const int kk4 = (tid & 15) * 4, jr = tid >> 4;
    #pragma unroll
    for (int p = 0; p < 4; ++p) {
        const int j = jr + p * 16;
        ushort4 o;
        o.x = f2bf(tile[kk4 + 0][j]); o.y = f2bf(tile[kk4 + 1][j]);
        o.z = f2bf(tile[kk4 + 2][j]); o.w = f2bf(tile[kk4 + 3][j]);
        *(ushort4*)(WpT + (size_t)(j0 + j) * DIM + k0 + kk4) = o;
    }
}

// --- ccB[b][1536] bf16, p_switch = sigmoid(W_u@c_cat+b_u), p_copy ---------
__global__ void k_pswitch(const float* __restrict__ h_t,
                          const float* __restrict__ W_u,
                          const float* __restrict__ b_u,
                          float* __restrict__ out_copy,
                          float* __restrict__ ws) {
    const int b = blockIdx.x, tid = threadIdx.x;
    const float invE = 1.f / ws[WS_ESUM + b];
    const float invD = 1.f / ws[WS_ESUM + 64 + b];
    const float* Ce = ws + WS_CENC + b * DIM;
    const float* Cd = ws + WS_CDEC + b * DIM;
    ushort* ccB = (ushort*)(ws + WS_CCB);
    __shared__ float red[256];
    float part = 0.f;
    #pragma unroll
    for (int r = 0; r < 6; ++r) {
        const int j = tid + r * 256;
        float v = (j < DIM) ? h_t[b * DIM + j]
                            : ((j < 2 * DIM) ? Ce[j - DIM] * invE : Cd[j - 2 * DIM] * invD);
        ccB[(size_t)b * K3 + j] = f2bf(v);
        part += W_u[j] * v;
    }
    red[tid] = part;
    __syncthreads();
    for (int s = 128; s > 0; s >>= 1) {
        if (tid < s) red[tid] += red[tid + s];
        __syncthreads();
    }
    const float ps = 1.f / (1.f + expf(-(red[0] + b_u[0])));
    if (tid == 0) ws[WS_PSW + b] = ps;
    const float* Ee = ws + WS_EENC + b * SRC;
    for (int i = tid; i < SRC; i += 256) out_copy[b * SRC + i] = ps * Ee[i] * invE;
}

// ---- MFMA fused: logits[v][b] = tanh(We@Wp)[v,:] @ ccB[b,:] + b_out[v] ----
#define VB 32
__global__ __launch_bounds__(256, 3) void k_bigmm(const float* __restrict__ We,
                                                  const float* __restrict__ ws,
                                                  const float* __restrict__ b_out,
                                                  float* __restrict__ out) {
    __shared__ __align__(16) char smem[49152];
    ushort* WeS = (ushort*)smem;             // [32 v][512 k] bf16, XOR-swizzled (32 KB)
    char*   Tscb = smem + 32768;             // [4 w][32 v][64 j] bf16, swizzled (16 KB)
    float*  Lred = (float*)smem;             // [4 w][32 v][65 b] f32 (overlaps, post-sync)

    const ushort* WpT = (const ushort*)(ws + WS_WPT);
    const ushort* ccB = (const ushort*)(ws + WS_CCB);

    const int tid  = threadIdx.x;
    const int w    = tid >> 6, lane = tid & 63;
    const int lrow = lane & 15, lgrp = lane >> 4;
    const int v0   = blockIdx.x * VB;

    // ---- stage We rows -> bf16 LDS, swizzle byte ^= (v&15)<<4 ----
    for (int it = 0; it < 8; ++it) {
        const int idx = it * 256 + tid;
        const int v = idx >> 6;
        const int k0 = (idx & 63) * 8;
        const int row = v0 + v;
        float4 f0 = {0.f, 0.f, 0.f, 0.f}, f1 = {0.f, 0.f, 0.f, 0.f};
        if (row < NEMB) {
            f0 = *(const float4*)(We + (size_t)row * DIM + k0);
            f1 = *(const float4*)(We + (size_t)row * DIM + k0 + 4);
        }
        union { ushort us[8]; bf16x8 v8; } pk;
        pk.us[0] = f2bf(f0.x); pk.us[1] = f2bf(f0.y); pk.us[2] = f2bf(f0.z); pk.us[3] = f2bf(f0.w);
        pk.us[4] = f2bf(f1.x); pk.us[5] = f2bf(f1.y); pk.us[6] = f2bf(f1.z); pk.us[7] = f2bf(f1.w);
        *(bf16x8*)((char*)WeS + v * 1024 + ((k0 * 2) ^ ((v & 15) << 4))) = pk.v8;
    }
    __syncthreads();

    f32x4 La[8];
    #pragma unroll
    for (int i = 0; i < 8; ++i) La[i] = (f32x4){0.f, 0.f, 0.f, 0.f};

    char* tbase = Tscb + w * 4096;
    const int swz0 = (lrow & 15) << 4;
    const int swz1 = ((16 + lrow) & 15) << 4;
    const int tswz0 = (lrow & 7) << 4;
    const int tswz1 = ((16 + lrow) & 7) << 4;
    const char* weRow0 = (char*)WeS + lrow * 1024;
    const char* weRow1 = (char*)WeS + (16 + lrow) * 1024;

    for (int t = 0; t < 6; ++t) {
        const int jc = w + 4 * t;
        const int j0 = jc * 64;
        const ushort* wpBase = WpT + (size_t)(j0 + lrow) * DIM + lgrp * 8;
        f32x4 Ta[8];
        #pragma unroll
        for (int i = 0; i < 8; ++i) Ta[i] = (f32x4){0.f, 0.f, 0.f, 0.f};

        // ---- GEMM1 with explicit 1-deep register prefetch, full unroll ----
        bf16x8 a0c = *(bf16x8*)(weRow0 + ((lgrp * 16) ^ swz0));
        bf16x8 a1c = *(bf16x8*)(weRow1 + ((lgrp * 16) ^ swz1));
        bf16x8 b0c = *(const bf16x8*)(wpBase);
        bf16x8 b1c = *(const bf16x8*)(wpBase + 16 * DIM);
        bf16x8 b2c = *(const bf16x8*)(wpBase + 32 * DIM);
        bf16x8 b3c = *(const bf16x8*)(wpBase + 48 * DIM);
        #pragma unroll
        for (int ks = 0; ks < 16; ++ks) {
            bf16x8 a0n, a1n, b0n, b1n, b2n, b3n;
            if (ks < 15) {
                const int kb = (ks + 1) * 64 + lgrp * 16;
                a0n = *(bf16x8*)(weRow0 + (kb ^ swz0));
                a1n = *(bf16x8*)(weRow1 + (kb ^ swz1));
                const int kk = (ks + 1) * 32;
                b0n = *(const bf16x8*)(wpBase + kk);
                b1n = *(const bf16x8*)(wpBase + 16 * DIM + kk);
                b2n = *(const bf16x8*)(wpBase + 32 * DIM + kk);
                b3n = *(const bf16x8*)(wpBase + 48 * DIM + kk);
            }
            Ta[0] = __builtin_amdgcn_mfma_f32_16x16x32_bf16(a0c, b0c, Ta[0], 0, 0, 0);
            Ta[4] = __builtin_amdgcn_mfma_f32_16x16x32_bf16(a1c, b0c, Ta[4], 0, 0, 0);
            Ta[1] = __builtin_amdgcn_mfma_f32_16x16x32_bf16(a0c, b1c, Ta[1], 0, 0, 0);
            Ta[5] = __builtin_amdgcn_mfma_f32_16x16x32_bf16(a1c, b1c, Ta[5], 0, 0, 0);
            Ta[2] = __builtin_amdgcn_mfma_f32_16x16x32_bf16(a0c, b2c, Ta[2], 0, 0, 0);
            Ta[6] = __builtin_amdgcn_mfma_f32_16x16x32_bf16(a1c, b2c, Ta[6], 0, 0, 0);
            Ta[3] = __builtin_amdgcn_mfma_f32_16x16x32_bf16(a0c, b3c, Ta[3], 0, 0, 0);
            Ta[7] = __builtin_amdgcn_mfma_f32_16x16x32_bf16(a1c, b3c, Ta[7], 0, 0, 0);
            if (ks < 15) {
                a0c = a0n; a1c = a1n;
                b0c = b0n; b1c = b1n; b2c = b2n; b3c = b3n;
            }
        }

        // ---- prefetch ccB fragments (independent of T) ----
        bf16x8 cb0[4], cb1[4];
        #pragma unroll
        for (int nb = 0; nb < 4; ++nb) {
            const ushort* cr = ccB + (size_t)(nb * 16 + lrow) * K3 + j0 + lgrp * 8;
            cb0[nb] = *(const bf16x8*)(cr);
            cb1[nb] = *(const bf16x8*)(cr + 32);
        }

        // ---- tanh -> bf16 -> per-wave LDS scratch (C-layout -> A-layout) ----
        #pragma unroll
        for (int i = 0; i < 8; ++i) {
            const int mv = i >> 2, nj = i & 3;
            const int jb = (nj * 16 + lrow) * 2;
            #pragma unroll
            for (int r = 0; r < 4; ++r) {
                const int v = mv * 16 + lgrp * 4 + r;
                const float th = fast_tanh(Ta[i][r]);
                *(ushort*)(tbase + v * 128 + (jb ^ ((v & 7) << 4))) = f2bf(th);
            }
        }

        // ---- GEMM2: La[32 v][64 b] += T[32][64] @ ccB^T slice ----
        bf16x8 t00 = *(bf16x8*)(tbase + lrow * 128 + ((lgrp * 16) ^ tswz0));
        bf16x8 t01 = *(bf16x8*)(tbase + (16 + lrow) * 128 + ((lgrp * 16) ^ tswz1));
        bf16x8 t10 = *(bf16x8*)(tbase + lrow * 128 + ((64 + lgrp * 16) ^ tswz0));
        bf16x8 t11 = *(bf16x8*)(tbase + (16 + lrow) * 128 + ((64 + lgrp * 16) ^ tswz1));
        #pragma unroll
        for (int nb = 0; nb < 4; ++nb) {
            La[nb]     = __builtin_amdgcn_mfma_f32_16x16x32_bf16(t00, cb0[nb], La[nb], 0, 0, 0);
            La[4 + nb] = __builtin_amdgcn_mfma_f32_16x16x32_bf16(t01, cb0[nb], La[4 + nb], 0, 0, 0);
        }
        #pragma unroll
        for (int nb = 0; nb < 4; ++nb) {
            La[nb]     = __builtin_amdgcn_mfma_f32_16x16x32_bf16(t10, cb1[nb], La[nb], 0, 0, 0);
            La[4 + nb] = __builtin_amdgcn_mfma_f32_16x16x32_bf16(t11, cb1[nb], La[4 + nb], 0, 0, 0);
        }
    }

    // ---- cross-wave reduction of logits partials ----
    __syncthreads();
    #pragma unroll
    for (int i = 0; i < 8; ++i) {
        const int mv = i >> 2, nb = i & 3;
        const int b = nb * 16 + lrow;
        #pragma unroll
        for (int r = 0; r < 4; ++r) {
            const int v = mv * 16 + lgrp * 4 + r;
            Lred[w * 2080 + v * 65 + b] = La[i][r];
        }
    }
    __syncthreads();
    for (int it = 0; it < 8; ++it) {
        const int idx = it * 256 + tid;
        const int b = idx >> 5;
        const int v = idx & 31;
        if (v0 + v < NEMB) {
            const float s = Lred[v * 65 + b] + Lred[2080 + v * 65 + b]
                          + Lred[4160 + v * 65 + b] + Lred[6240 + v * 65 + b];
            out[(size_t)b * NEMB + v0 + v] = s + b_out[v0 + v];
        }
    }
}

// -------- per-b max over vocab (split 4-way, atomicMax on encoded bits) ----
#define VC 12565
__global__ void k_colmax(const float* __restrict__ out, float* __restrict__ ws) {
    const int b = blockIdx.x, vc = blockIdx.y, tid = threadIdx.x;
    const float* L = out + (size_t)b * NEMB;
    const int vend = min((vc + 1) * VC, NEMB);
    float m = -1e30f;
    for (int v = vc * VC + tid; v < vend; v += 256) m = fmaxf(m, L[v]);
    __shared__ float red[256];
    red[tid] = m;
    __syncthreads();
    for (int s = 128; s > 0; s >>= 1) {
        if (tid < s) red[tid] = fmaxf(red[tid], red[tid + s]);
        __syncthreads();
    }
    if (tid == 0) atomicMax((unsigned*)(ws + WS_SMAX) + b, fenc(red[0]));
}

__global__ void k_colsum(const float* __restrict__ out, float* __restrict__ ws) {
    const int b = blockIdx.x, vc = blockIdx.y, tid = threadIdx.x;
    const float* L = out + (size_t)b * NEMB;
    const float mb = fdec(((const unsigned*)(ws + WS_SMAX))[b]);
    const int vend = min((vc + 1) * VC, NEMB);
    float sum = 0.f;
    for (int v = vc * VC + tid; v < vend; v += 256) sum += expf(L[v] - mb);
    __shared__ float red[256];
    red[tid] = sum;
    __syncthreads();
    for (int s = 128; s > 0; s >>= 1) {
        if (tid < s) red[tid] += red[tid + s];
        __syncthreads();
    }
    if (tid == 0) atomicAdd(ws + WS_SSUM + b, red[0]);
}

// -------- p_gen[b,v] = (1-p_switch[b]) * softmax(logits)[v,b], in place ----
__global__ void k_finalize(float* __restrict__ out, const float* __restrict__ ws) {
    const int total = BS * NEMB;
    const int stride = gridDim.x * blockDim.x;
    for (int idx = blockIdx.x * blockDim.x + threadIdx.x; idx < total; idx += stride) {
        const int b = idx / NEMB;
        const float mb = fdec(((const unsigned*)(ws + WS_SMAX))[b]);
        const float sb = ws[WS_SSUM + b];
        const float ps = ws[WS_PSW + b];
        out[idx] = (1.f - ps) * expf(out[idx] - mb) / sb;
    }
}

extern "C" void kernel_launch(void* const* d_in, const int* in_sizes, int n_in,
                              void* d_out, int out_size, void* d_ws, size_t ws_size,
                              hipStream_t stream) {
    const float* h_t        = (const float*)d_in[0];
    const float* h_enc      = (const float*)d_in[1];
    const float* h_dec      = (const float*)d_in[2];
    const float* W_attn_enc = (const float*)d_in[4];
    const float* W_attn_dec = (const float*)d_in[5];
    const float* W_emb      = (const float*)d_in[6];
    const float* W_proj     = (const float*)d_in[7];
    const float* W_u        = (const float*)d_in[8];
    const float* b_u        = (const float*)d_in[9];
    const float* b_out      = (const float*)d_in[10];

    float* out = (float*)d_out;
    float* ws  = (float*)d_ws;
    float* out_copy = out + (size_t)BS * NEMB;

    k_zero   <<<(WS_ZCNT + 255) / 256, 256, 0, stream>>>(ws);
    k_qk     <<<dim3(64, 2), 256, 0, stream>>>(h_t, W_attn_enc, W_attn_dec, ws);
    k_prepWpT<<<dim3(24, 8), 256, 0, stream>>>(W_proj, ws);
    k_attn   <<<dim3(64, 2, 4), 256, 0, stream>>>(h_enc, h_dec, ws);
    k_pswitch<<<64, 256, 0, stream>>>(h_t, W_u, b_u, out_copy, ws);
    k_bigmm  <<<(NEMB + VB - 1) / VB, 256, 0, stream>>>(W_emb, ws, b_out, out);
    k_colmax <<<dim3(64, 4), 256, 0, stream>>>(out, ws);
    k_colsum <<<dim3(64, 4), 256, 0, stream>>>(out, ws);
    k_finalize<<<4096, 256, 0, stream>>>(out, ws);
}